// Round 6
// baseline (15.096 us; speedup 1.0000x reference)
//
#include <hip/hip_runtime.h>

static constexpr int NPIX = 256 * 256;
static constexpr int NF4 = NPIX / 4;  // 16384 f4 per plane

typedef float f4 __attribute__((ext_vector_type(4)));

// v6 = relu(relu(3*v2)+3) — monotone non-decreasing in v2 (as are v8, v21),
// so global min/max of the chained values are the chains applied to min/max(v2).
__device__ __forceinline__ float chain_v6(float v2) {
    return fmaxf(fmaxf(3.0f * v2, 0.0f) + 3.0f, 0.0f);
}
__device__ __forceinline__ float chain_v21(float v2) {
    float t = 3.0f * chain_v6(v2);
    t = fmaxf(t - 3.0f, 0.0f);
    t = fmaxf(t - 3.0f, 0.0f);
    t = fmaxf(t - 3.0f, 0.0f);
    return t - 6.0f;
}

__device__ __forceinline__ f4 vmax(f4 a, f4 b) {
    return f4{fmaxf(a.x, b.x), fmaxf(a.y, b.y), fmaxf(a.z, b.z), fmaxf(a.w, b.w)};
}
__device__ __forceinline__ f4 vmin(f4 a, f4 b) {
    return f4{fminf(a.x, b.x), fminf(a.y, b.y), fminf(a.z, b.z), fminf(a.w, b.w)};
}

// k1: one thread per 4 pixels (f4). 128 blocks x 128 threads = 16384 threads.
// Writes per-pixel batch-max M[3][NPIX] (f4) and per-block (max,min) of v2.
__global__ __launch_bounds__(128) void k_compute(const f4* __restrict__ x,
                                                 const float* __restrict__ Wp,
                                                 const float* __restrict__ bp,
                                                 f4* __restrict__ Mv,
                                                 float2* __restrict__ partials) {
    const int t = threadIdx.x;
    const int p4 = blockIdx.x * 128 + t;  // f4-pixel index, 0..16383
    const int lane = t & 63, wid = t >> 6;

    float W[9];
#pragma unroll
    for (int i = 0; i < 9; ++i) W[i] = Wp[i];  // torch (in,out) layout
    const float bias[3] = {bp[0], bp[1], bp[2]};

    f4 Mc[3];
#pragma unroll
    for (int c = 0; c < 3; ++c) Mc[c] = f4{-3.4e38f, -3.4e38f, -3.4e38f, -3.4e38f};
    f4 mn = f4{3.4e38f, 3.4e38f, 3.4e38f, 3.4e38f};

#pragma unroll
    for (int b = 0; b < 6; ++b) {
        const f4 x0 = __builtin_nontemporal_load(&x[(b * 3 + 0) * NF4 + p4]);
        const f4 x1 = __builtin_nontemporal_load(&x[(b * 3 + 1) * NF4 + p4]);
        const f4 x2 = __builtin_nontemporal_load(&x[(b * 3 + 2) * NF4 + p4]);
#pragma unroll
        for (int c = 0; c < 3; ++c) {
            f4 v2 = x0 * W[c] + x1 * W[3 + c] + x2 * W[6 + c] + (bias[c] + 3.0f);
            Mc[c] = vmax(Mc[c], v2);
            mn = vmin(mn, v2);
        }
    }

    Mv[0 * NF4 + p4] = Mc[0];
    Mv[1 * NF4 + p4] = Mc[1];
    Mv[2 * NF4 + p4] = Mc[2];

    f4 mx4 = vmax(Mc[0], vmax(Mc[1], Mc[2]));
    float maxv2 = fmaxf(fmaxf(mx4.x, mx4.y), fmaxf(mx4.z, mx4.w));
    float minv2 = fminf(fminf(mn.x, mn.y), fminf(mn.z, mn.w));

#pragma unroll
    for (int o = 32; o > 0; o >>= 1) {
        maxv2 = fmaxf(maxv2, __shfl_down(maxv2, o));
        minv2 = fminf(minv2, __shfl_down(minv2, o));
    }
    __shared__ float smx[2], smn[2];
    if (lane == 0) { smx[wid] = maxv2; smn[wid] = minv2; }
    __syncthreads();
    if (t == 0) {
        partials[blockIdx.x] = make_float2(fmaxf(smx[0], smx[1]), fminf(smn[0], smn[1]));
    }
}

// k2: 768 blocks x 192 threads. Block xr: thread (c=t/64, l=t&63) loads one f4
// of M[c][xr%256][:] and stores (+S) to 9 positions: rows k=c,c+3,c+6 at
// w4 = l, l+64, l+128 (out[...][w] = M[..][w%256] periodicity).
__global__ __launch_bounds__(192) void k_out(const f4* __restrict__ Mv,
                                             const float2* __restrict__ partials,
                                             f4* __restrict__ out) {
    const int t = threadIdx.x;
    __shared__ float sS;

    if (t < 64) {
        float2 p0 = partials[t];
        float2 p1 = partials[t + 64];
        float A = fmaxf(p0.x, p1.x), B = fminf(p0.y, p1.y);
#pragma unroll
        for (int o = 32; o > 0; o >>= 1) {
            A = fmaxf(A, __shfl_down(A, o));
            B = fminf(B, __shfl_down(B, o));
        }
        if (t == 0) {
            // out = m1 + max(v2) + 2*min(v6) + max(v8) + min(v21)
            sS = A + 2.0f * chain_v6(B) + (3.0f * chain_v6(A) + 3.0f) + chain_v21(B);
        }
    }
    __syncthreads();
    const float S = sS;

    const int c = t >> 6, l = t & 63;
    const int xr = blockIdx.x;  // 0..767

    const f4 r = Mv[c * NF4 + (xr & 255) * 64 + l] + S;
    const int base = (xr * 9 + c) * 192 + l;
#pragma unroll
    for (int k = 0; k < 3; ++k) {
#pragma unroll
        for (int w = 0; w < 3; ++w) {
            __builtin_nontemporal_store(r, &out[base + k * 576 + w * 64]);
        }
    }
}

extern "C" void kernel_launch(void* const* d_in, const int* in_sizes, int n_in,
                              void* d_out, int out_size, void* d_ws, size_t ws_size,
                              hipStream_t stream) {
    const f4* x = (const f4*)d_in[0];         // [6,3,256,256]
    const float* W = (const float*)d_in[1];   // [3,3] (in,out)
    const float* b = (const float*)d_in[2];   // [3]

    f4* Mv = (f4*)d_ws;                                          // 3*16384 f4
    float2* partials = (float2*)((char*)d_ws + 3 * NPIX * 4);    // 128 float2

    hipLaunchKernelGGL(k_compute, dim3(128), dim3(128), 0, stream, x, W, b, Mv, partials);
    hipLaunchKernelGGL(k_out, dim3(768), dim3(192), 0, stream, Mv, partials, (f4*)d_out);
}